// Round 17
// baseline (225.523 us; speedup 1.0000x reference)
//
#include <hip/hip_runtime.h>
#include <hip/hip_bf16.h>
#include <math.h>

#define BQ 32
#define SQ 2048
#define DQ 1024
#define NQ 512
#define MQ (BQ*SQ)
#define BM 256
#define BN 256
#define BK 64

typedef __attribute__((ext_vector_type(8))) short bf16x8;
typedef __attribute__((ext_vector_type(4))) float f32x4;

// compiler-path f32->bf16 (RTNE, pairs into v_cvt_pk_bf16_f32)
__device__ __forceinline__ short f2bf(float f){
  return __builtin_bit_cast(short, __float2bfloat16(f));
}

__device__ __forceinline__ void gload_lds16(const void* g, void* l){
  __builtin_amdgcn_global_load_lds(
      (const __attribute__((address_space(1))) unsigned int*)g,
      (__attribute__((address_space(3))) unsigned int*)l, 16, 0, 0);
}

// ---- mask dtype detector: 0=int32(0/1), 1=float32(0/1.0f), 2=byte(bool)
__global__ void k_det(const uint4* __restrict__ m, int* __restrict__ flag){
  __shared__ int so, sf;
  int t = threadIdx.x;
  if (t==0){ so=0; sf=0; }
  __syncthreads();
  int o=0, f1=0;
  #pragma unroll 4
  for (int i=t;i<MQ/16;i+=256){
    uint4 v = m[i];
    if (v.x==0x3F800000u||v.y==0x3F800000u||v.z==0x3F800000u||v.w==0x3F800000u) f1=1;
    else if (v.x>1u||v.y>1u||v.z>1u||v.w>1u) o=1;
  }
  if (o) atomicOr(&so,1);
  if (f1) atomicOr(&sf,1);
  __syncthreads();
  if (t==0) *flag = so?2:(sf?1:0);
}

// ---- merged prep (r16): w1 transpose (LDS-tiled) + wq + lens
__global__ __launch_bounds__(256) void k_prep(
    const float* __restrict__ w1, short* __restrict__ w1t,
    const float* __restrict__ kw, const float* __restrict__ kb,
    const float* __restrict__ q, float* __restrict__ wq,
    const void* __restrict__ maskp, const int* __restrict__ flag,
    int* __restrict__ lens)
{
  __shared__ float tile[64][65];
  int blk = blockIdx.x, t = threadIdx.x;
  if (blk < 128){
    int kt = blk >> 3, nt = blk & 7;
    int c = t & 63, rq = t >> 6;
    #pragma unroll
    for (int i=0;i<16;i++){
      int r = rq + i*4;
      tile[r][c] = w1[(size_t)(kt*64 + r)*NQ + nt*64 + c];
    }
    __syncthreads();
    #pragma unroll
    for (int i=0;i<16;i++){
      int nr = rq + i*4;
      w1t[(size_t)(nt*64 + nr)*DQ + kt*64 + c] = f2bf(tile[c][nr]);
    }
  } else if (blk < 1153){
    int d = blk - 128;
    const float* row = (d < DQ) ? (kw + (size_t)d*DQ) : kb;
    float s = 0.f;
    for (int e=t;e<DQ;e+=256) s += row[e]*q[e];
    #pragma unroll
    for (int o=32;o;o>>=1) s += __shfl_down(s,o);
    if ((t&63)==0) tile[0][t>>6]=s;
    __syncthreads();
    if (t==0) wq[d] = tile[0][0]+tile[0][1]+tile[0][2]+tile[0][3];
  } else {
    int b = blk - 1153;
    int fl = *flag;
    const unsigned char* m8 = (const unsigned char*)maskp;
    const float* mf = (const float*)maskp;
    const int* mi = (const int*)maskp;
    int cnt = 0;
    #pragma unroll
    for (int i=0;i<8;i++){
      size_t idx = (size_t)b*SQ + t + i*256;
      int mm = (fl==2) ? (m8[idx]!=0) : (fl==1) ? (mf[idx]!=0.0f) : (mi[idx]!=0);
      cnt += mm^1;
    }
    #pragma unroll
    for (int o=32;o;o>>=1) cnt += __shfl_down(cnt,o);
    if ((t&63)==0) tile[0][t>>6]=(float)cnt;
    __syncthreads();
    if (t==0) lens[b] = (int)(tile[0][0]+tile[0][1]+tile[0][2]+tile[0][3]);
  }
}

// ---- big-tile deep-interval GEMM: 256x256 tile, BK=64, 512 thr = 8 waves
// (2m x 4n), wave tile 128x64, acc 8x4 f32x4 (128 AGPR), 1 block/CU.
// Per iter: 64 MFMA/wave (~640cy/SIMD) between barriers -> staging issued at
// iter top has a full iter in flight before the drain. A reg-staged
// (f32->cvt->LDS, xq fused, chunk-XOR swizzle write+read); B via
// global_load_lds with pre-swizzled GLOBAL source + swizzled read (T2/#21).
__global__ __launch_bounds__(512, 2) void k_gate(
    const float* __restrict__ x, const short* __restrict__ w1t,
    const float* __restrict__ wq, const float* __restrict__ w2,
    const float* __restrict__ b1,
    float* __restrict__ gpart, float* __restrict__ xq)
{
  __shared__ __align__(16) short As[2][BM*BK];   // 32KB x2
  __shared__ __align__(16) short Bs[2][BN*BK];   // 32KB x2
  __shared__ float wqs[DQ];                       // 4KB  (132KB total)

  int tid = threadIdx.x;
  int phys = blockIdx.x;
  int bid = ((phys & 7) << 6) | (phys >> 3);     // 512 blocks, XCD chunks of 64
  int bm = bid >> 1, bn = bid & 1;
  int m0 = bm*BM, n0 = bn*BN;
  int lane = tid & 63, wid = tid >> 6;
  int wm = wid >> 2, wn = wid & 3;               // wave tile 128x64
  int lo = lane & 15, hi = lane >> 4;
  int lo7 = lo & 7;

  // A staging: thread -> row tid>>1, float-half (tid&1)*32 (8 f32x4)
  int arow = tid >> 1;
  int ah   = (tid & 1) * 32;
  int ac0  = (tid & 1) * 4;        // first bf16 chunk (8 shorts per chunk)
  int arow7 = arow & 7;
  const float* abase = x + (size_t)(m0 + arow)*DQ + ah;
  // B staging: issue i covers rows i*64+(tid>>3); pre-swizzled global chunk
  int brow = tid >> 3;
  int bchunk = (tid & 7) ^ (brow & 7);
  const short* bbase = w1t + (size_t)(n0 + brow)*DQ + bchunk*8;

  float w2v[4], b1v[4];
  #pragma unroll
  for (int fn=0;fn<4;fn++){
    int n = n0 + wn*64 + fn*16 + lo;
    w2v[fn] = w2[n]; b1v[fn] = b1[n];
  }

  // ---- prologue: stage tile 0
  wqs[tid]     = wq[tid];
  wqs[tid+512] = wq[tid+512];
  f32x4 a[8];
  #pragma unroll
  for (int j=0;j<8;j++) a[j] = *(const f32x4*)(abase + 4*j);
  #pragma unroll
  for (int i=0;i<4;i++)
    gload_lds16(bbase + (size_t)(i*64)*DQ, &Bs[0][i*4096 + tid*8]);
  __syncthreads();   // wqs visible (one-time full drain)
  float xqacc = 0.f;
  if (bn == 0){
    #pragma unroll
    for (int j=0;j<8;j++){
      f32x4 w = *(const f32x4*)(wqs + ah + 4*j);
      xqacc += a[j][0]*w[0] + a[j][1]*w[1] + a[j][2]*w[2] + a[j][3]*w[3];
    }
  }
  #pragma unroll
  for (int j=0;j<4;j++){
    bf16x8 sv;
    #pragma unroll
    for (int e=0;e<4;e++){ sv[e]=f2bf(a[2*j][e]); sv[4+e]=f2bf(a[2*j+1][e]); }
    *(bf16x8*)(&As[0][arow*64 + (((ac0+j) ^ arow7)<<3)]) = sv;
  }
  __syncthreads();   // As[0]/Bs[0] ready

  f32x4 acc[8][4];
  #pragma unroll
  for (int i=0;i<8;i++)
    #pragma unroll
    for (int jj=0;jj<4;jj++) acc[i][jj] = (f32x4){0.f,0.f,0.f,0.f};

  for (int t=0; t<16; ++t){
    int cur = t & 1, nxt = cur ^ 1;
    int k1 = (t+1)*BK;
    // stage tile t+1: A f32 loads first (consumed late-iter), then B gloads
    if (t < 15){
      #pragma unroll
      for (int j=0;j<8;j++) a[j] = *(const f32x4*)(abase + k1 + 4*j);
      #pragma unroll
      for (int i=0;i<4;i++)
        gload_lds16(bbase + (size_t)(i*64)*DQ + k1, &Bs[nxt][i*4096 + tid*8]);
    }
    // compute tile t: 64 MFMA/wave
    #pragma unroll
    for (int ks=0; ks<2; ++ks){
      bf16x8 bfr[4];
      #pragma unroll
      for (int fn=0;fn<4;fn++){
        int r = wn*64 + fn*16 + lo;
        bfr[fn] = *(const bf16x8*)(&Bs[cur][r*64 + (((ks*4+hi) ^ lo7)<<3)]);
      }
      #pragma unroll
      for (int fm=0;fm<8;fm++){
        int r = wm*128 + fm*16 + lo;
        bf16x8 af = *(const bf16x8*)(&As[cur][r*64 + (((ks*4+hi) ^ lo7)<<3)]);
        #pragma unroll
        for (int fn=0;fn<4;fn++)
          acc[fm][fn] = __builtin_amdgcn_mfma_f32_16x16x32_bf16(af, bfr[fn], acc[fm][fn], 0,0,0);
      }
    }
    // A(t+1): xq dot + convert + swizzled ds_write (auto-wait leaves B in flight
    // since A loads were issued BEFORE the B gloads)
    if (t < 15){
      if (bn == 0){
        #pragma unroll
        for (int j=0;j<8;j++){
          f32x4 w = *(const f32x4*)(wqs + k1 + ah + 4*j);
          xqacc += a[j][0]*w[0] + a[j][1]*w[1] + a[j][2]*w[2] + a[j][3]*w[3];
        }
      }
      #pragma unroll
      for (int j=0;j<4;j++){
        bf16x8 sv;
        #pragma unroll
        for (int e=0;e<4;e++){ sv[e]=f2bf(a[2*j][e]); sv[4+e]=f2bf(a[2*j+1][e]); }
        *(bf16x8*)(&As[nxt][arow*64 + (((ac0+j) ^ arow7)<<3)]) = sv;
      }
      __syncthreads();   // drains B(t+1) (in flight for the whole iter) + A writes
    }
  }

  // xq: combine the 2 threads per row
  if (bn == 0){
    float s = xqacc;
    s += __shfl_xor(s, 1);
    if ((tid & 1) == 0) xq[m0 + arow] = s;
  }

  // epilogue: GELU + dot w2 over this wave's 64 cols -> strip p = bn*4+wn
  #pragma unroll
  for (int fm=0;fm<8;fm++){
    #pragma unroll
    for (int j=0;j<4;j++){
      float s = 0.f;
      #pragma unroll
      for (int fn=0;fn<4;fn++){
        float h = acc[fm][fn][j] + b1v[fn];
        float g = 0.5f*h*(1.0f + erff(h*0.70710678118f));
        s += g*w2v[fn];
      }
      s += __shfl_xor(s,1); s += __shfl_xor(s,2);
      s += __shfl_xor(s,4); s += __shfl_xor(s,8);
      if (lo == 0){
        int p = bn*4 + wn;
        gpart[(size_t)p*MQ + m0 + wm*128 + fm*16 + hi*4 + j] = s;
      }
    }
  }
}

// ---- fused w-phase + pooling: 1024 blocks x 64 rows.
__global__ __launch_bounds__(256) void k_wpool(
    const float* __restrict__ x, const float* __restrict__ gpart,
    const float* __restrict__ xqv, const float* __restrict__ wq,
    const float* __restrict__ b2p, const float* __restrict__ lamp,
    const void* __restrict__ maskp, const int* __restrict__ flag,
    const int* __restrict__ lens,
    float* __restrict__ part, float* __restrict__ wsumv)
{
  __shared__ float wrow[64];
  int blk = blockIdx.x, t = threadIdx.x;
  int batch = blk >> 5;
  int sBase = (blk & 31) * 64;
  size_t R0 = (size_t)blk * 64;
  if (t < 64){
    size_t r = R0 + t;
    float gsum = b2p[0];
    #pragma unroll
    for (int p=0;p<8;p++) gsum += gpart[(size_t)p*MQ + r];
    float gate = 1.0f/(1.0f+expf(-gsum));
    float qb = wq[DQ];
    float lg = (gate*xqv[r] + qb)*0.03125f;
    float lam = lamp[0];
    float posl = fmaxf(lam,0.f) + log1pf(expf(-fabsf(lam)));
    int L = lens[batch];
    int s = sBase + t;
    float pen = fmaxf((float)L - 1.0f - (float)s, 0.0f);
    int fl = *flag;
    size_t mi_ = (size_t)batch*SQ + s;
    int mm = (fl==2) ? (((const unsigned char*)maskp)[mi_]!=0)
           : (fl==1) ? (((const float*)maskp)[mi_]!=0.0f)
                     : (((const int*)maskp)[mi_]!=0);
    float e = mm ? 0.0f : expf(lg - posl*pen);
    wrow[t] = e*gate;
    float ts = e;
    #pragma unroll
    for (int o=1;o<64;o<<=1) ts += __shfl_xor(ts,o);
    if (t==0) wsumv[blk] = ts;
  }
  __syncthreads();

  int d0 = t*4;
  const float* xb = x + R0*DQ + d0;
  f32x4 aa = {0.f,0.f,0.f,0.f};
  #pragma unroll 8
  for (int s=0;s<64;s++){
    float w = wrow[s];
    f32x4 v = *(const f32x4*)(xb + (size_t)s*DQ);
    aa[0] += w*v[0]; aa[1] += w*v[1]; aa[2] += w*v[2]; aa[3] += w*v[3];
  }
  *(f32x4*)(part + (size_t)blk*DQ + d0) = aa;
}

// ---- final: out[b][d] = sum_c part[b*32+c][d] / sum_c wsum[b*32+c]
__global__ __launch_bounds__(256) void k_fin(const float* __restrict__ part,
                                             const float* __restrict__ wsumv,
                                             float* __restrict__ out){
  int i = blockIdx.x*256 + threadIdx.x;   // 32768
  int b = i >> 10, d = i & 1023;
  float den = 0.f;
  #pragma unroll
  for (int c=0;c<32;c++) den += wsumv[b*32+c];
  float s = 0.f;
  #pragma unroll
  for (int c=0;c<32;c++) s += part[((size_t)(b*32+c))*DQ + d];
  out[i] = s/den;
}

extern "C" void kernel_launch(void* const* d_in, const int* in_sizes, int n_in,
                              void* d_out, int out_size, void* d_ws, size_t ws_size,
                              hipStream_t stream)
{
  const float* x    = (const float*)d_in[0];
  const void*  mask = d_in[1];
  const float* w1   = (const float*)d_in[2];
  const float* b1   = (const float*)d_in[3];
  const float* w2   = (const float*)d_in[4];
  const float* b2   = (const float*)d_in[5];
  const float* lam  = (const float*)d_in[6];
  const float* q    = (const float*)d_in[7];
  const float* kw   = (const float*)d_in[8];
  const float* kb   = (const float*)d_in[9];
  char* ws = (char*)d_ws;
  short* w1t   = (short*)ws;                             // 1 MB
  float* wq    = (float*)(ws + (1<<20));                 // 8 KB (1025 floats)
  int*   flag  = (int*)(ws + (1<<20) + 8192);            // 4 B
  int*   lens  = (int*)(ws + (1<<20) + 8448);            // 128 B
  float* wsumv = (float*)(ws + (1<<20) + 12544);         // 4 KB (1024)
  float* xqv   = (float*)(ws + (1<<20) + 32768);         // 256 KB
  float* gpart = (float*)(ws + (2<<20));                 // 2 MB (8 x MQ)
  float* part  = (float*)(ws + (4<<20));                 // 4 MB (1024 x 1024)
  float* out   = (float*)d_out;

  k_det<<<dim3(1), 256, 0, stream>>>((const uint4*)mask, flag);
  k_prep<<<dim3(1185), 256, 0, stream>>>(w1, w1t, kw, kb, q, wq,
                                         mask, flag, lens);
  k_gate<<<dim3((MQ/BM)*(NQ/BN)), 512, 0, stream>>>(x, w1t, wq, w2, b1,
                                                    gpart, xqv);
  k_wpool<<<dim3(MQ/64), 256, 0, stream>>>(x, gpart, xqv, wq, b2, lam,
                                           mask, flag, lens, part, wsumv);
  k_fin<<<dim3((BQ*DQ)/256), 256, 0, stream>>>(part, wsumv, out);
}

// Round 18
// 170.973 us; speedup vs baseline: 1.3191x; 1.3191x over previous
//
#include <hip/hip_runtime.h>
#include <hip/hip_bf16.h>
#include <math.h>

#define BQ 32
#define SQ 2048
#define DQ 1024
#define NQ 512
#define MQ (BQ*SQ)
#define BM 128
#define BN 256
#define BK 32

typedef __attribute__((ext_vector_type(8))) short bf16x8;
typedef __attribute__((ext_vector_type(4))) float f32x4;

// compiler-path f32->bf16 (RTNE, pairs into v_cvt_pk_bf16_f32)
__device__ __forceinline__ short f2bf(float f){
  return __builtin_bit_cast(short, __float2bfloat16(f));
}

__device__ __forceinline__ void gload_lds16(const void* g, void* l){
  __builtin_amdgcn_global_load_lds(
      (const __attribute__((address_space(1))) unsigned int*)g,
      (__attribute__((address_space(3))) unsigned int*)l, 16, 0, 0);
}

// ---- mask dtype detector: 0=int32(0/1), 1=float32(0/1.0f), 2=byte(bool)
// Scans 64KB (safe for all dtypes) as uint4.
__global__ void k_det(const uint4* __restrict__ m, int* __restrict__ flag){
  __shared__ int so, sf;
  int t = threadIdx.x;
  if (t==0){ so=0; sf=0; }
  __syncthreads();
  int o=0, f1=0;
  #pragma unroll 4
  for (int i=t;i<MQ/16;i+=256){
    uint4 v = m[i];
    if (v.x==0x3F800000u||v.y==0x3F800000u||v.z==0x3F800000u||v.w==0x3F800000u) f1=1;
    else if (v.x>1u||v.y>1u||v.z>1u||v.w>1u) o=1;
  }
  if (o) atomicOr(&so,1);
  if (f1) atomicOr(&sf,1);
  __syncthreads();
  if (t==0) *flag = so?2:(sf?1:0);
}

// ---- merged prep:
// blocks [0,128): w1 [1024][512] -> bf16 w1t [512][1024], LDS-tiled transpose
// blocks [128,1153): wq[d] = key_w[d,:]·q (d<1024); wq[1024] = key_b·q
// blocks [1153,1185): per-batch valid length (reads flag)
__global__ __launch_bounds__(256) void k_prep(
    const float* __restrict__ w1, short* __restrict__ w1t,
    const float* __restrict__ kw, const float* __restrict__ kb,
    const float* __restrict__ q, float* __restrict__ wq,
    const void* __restrict__ maskp, const int* __restrict__ flag,
    int* __restrict__ lens)
{
  __shared__ float tile[64][65];
  int blk = blockIdx.x, t = threadIdx.x;
  if (blk < 128){
    int kt = blk >> 3, nt = blk & 7;    // 16 k-tiles x 8 n-tiles of 64x64
    int c = t & 63, rq = t >> 6;
    #pragma unroll
    for (int i=0;i<16;i++){
      int r = rq + i*4;                 // coalesced rows
      tile[r][c] = w1[(size_t)(kt*64 + r)*NQ + nt*64 + c];
    }
    __syncthreads();
    #pragma unroll
    for (int i=0;i<16;i++){
      int nr = rq + i*4;
      w1t[(size_t)(nt*64 + nr)*DQ + kt*64 + c] = f2bf(tile[c][nr]);
    }
  } else if (blk < 1153){
    int d = blk - 128;
    const float* row = (d < DQ) ? (kw + (size_t)d*DQ) : kb;
    float s = 0.f;
    for (int e=t;e<DQ;e+=256) s += row[e]*q[e];
    #pragma unroll
    for (int o=32;o;o>>=1) s += __shfl_down(s,o);
    if ((t&63)==0) tile[0][t>>6]=s;
    __syncthreads();
    if (t==0) wq[d] = tile[0][0]+tile[0][1]+tile[0][2]+tile[0][3];
  } else {
    int b = blk - 1153;
    int fl = *flag;
    const unsigned char* m8 = (const unsigned char*)maskp;
    const float* mf = (const float*)maskp;
    const int* mi = (const int*)maskp;
    int cnt = 0;
    #pragma unroll
    for (int i=0;i<8;i++){
      size_t idx = (size_t)b*SQ + t + i*256;
      int mm = (fl==2) ? (m8[idx]!=0) : (fl==1) ? (mf[idx]!=0.0f) : (mi[idx]!=0);
      cnt += mm^1;
    }
    #pragma unroll
    for (int o=32;o;o>>=1) cnt += __shfl_down(cnt,o);
    if ((t&63)==0) tile[0][t>>6]=(float)cnt;
    __syncthreads();
    if (t==0) lens[b] = (int)(tile[0][0]+tile[0][1]+tile[0][2]+tile[0][3]);
  }
}

// ---- fused MFMA GEMM (champion): h=x@W1 bf16, LDS dbuf,
// epilogue GELU·w2 partials -> gpart[8][MQ]; xq fused in A staging (bn==0).
// 128x256 tile, BK=32, 512 threads = 8 waves (2 wm x 4 wn), wave tile 64x64.
__global__ __launch_bounds__(512) void k_gate(
    const float* __restrict__ x, const short* __restrict__ w1t,
    const float* __restrict__ wq, const float* __restrict__ w2,
    const float* __restrict__ b1,
    float* __restrict__ gpart, float* __restrict__ xq)
{
  __shared__ __align__(16) short As[2][BM*BK];   // 8KB x2
  __shared__ __align__(16) short Bs[2][BN*BK];   // 16KB x2
  __shared__ float wqs[DQ];                       // 4KB

  int tid = threadIdx.x;
  int phys = blockIdx.x;
  int bid = ((phys & 7) << 7) | (phys >> 3);
  int bm = bid >> 1, bn = bid & 1;
  int m0 = bm*BM;
  int lane = tid & 63, wid = tid >> 6;
  int wm = wid >> 2, wn = wid & 3;
  int lo = lane & 15, hi = lane >> 4;

  wqs[tid]     = wq[tid];
  wqs[tid+512] = wq[tid+512];

  int ar = tid >> 2, ac = (tid & 3) * 8;
  const float* asrc = x + (size_t)(m0 + ar)*DQ + ac;
  const short* bsrc = w1t + (size_t)(bn*BN + (tid>>2))*DQ + (tid&3)*8;

  float w2v[4], b1v[4];
  #pragma unroll
  for (int fn=0;fn<4;fn++){
    int n = bn*BN + wn*64 + fn*16 + lo;
    w2v[fn] = w2[n]; b1v[fn] = b1[n];
  }

  // ---- prologue: stage k0=0
  f32x4 r0 = *(const f32x4*)(asrc);
  f32x4 r1 = *(const f32x4*)(asrc + 4);
  gload_lds16(bsrc,                    &Bs[0][tid*8]);
  gload_lds16(bsrc + (size_t)128*DQ,   &Bs[0][tid*8 + 4096]);
  __syncthreads();   // wqs visible; Bs[0] drained (barrier implies vmcnt(0))
  float xqacc = 0.f;
  {
    if (bn == 0){
      f32x4 w0 = *(const f32x4*)(wqs + ac);
      f32x4 w1v = *(const f32x4*)(wqs + ac + 4);
      #pragma unroll
      for (int j=0;j<4;j++)
        xqacc += r0[j]*w0[j] + r1[j]*w1v[j];
    }
    bf16x8 s0;
    #pragma unroll
    for (int j=0;j<4;j++){ s0[j]=f2bf(r0[j]); s0[4+j]=f2bf(r1[j]); }
    *(bf16x8*)(&As[0][ar*BK + ac]) = s0;
  }
  __syncthreads();

  f32x4 acc[4][4];
  #pragma unroll
  for (int a=0;a<4;a++)
    #pragma unroll
    for (int b=0;b<4;b++) acc[a][b] = (f32x4){0.f,0.f,0.f,0.f};

  for (int t=0;t<32;t++){
    int cur = t & 1, nxt = cur ^ 1;
    int k0n = (t+1)*BK;
    if (t < 31){
      r0 = *(const f32x4*)(asrc + k0n);
      r1 = *(const f32x4*)(asrc + k0n + 4);
      gload_lds16(bsrc + k0n,                  &Bs[nxt][tid*8]);
      gload_lds16(bsrc + (size_t)128*DQ + k0n, &Bs[nxt][tid*8 + 4096]);
    }
    bf16x8 af[4], bfr[4];
    #pragma unroll
    for (int fm=0;fm<4;fm++)
      af[fm] = *(const bf16x8*)(&As[cur][(wm*64+fm*16+lo)*BK + hi*8]);
    #pragma unroll
    for (int fn=0;fn<4;fn++)
      bfr[fn] = *(const bf16x8*)(&Bs[cur][(wn*64+fn*16+lo)*BK + hi*8]);
    #pragma unroll
    for (int fm=0;fm<4;fm++)
      #pragma unroll
      for (int fn=0;fn<4;fn++)
        acc[fm][fn] = __builtin_amdgcn_mfma_f32_16x16x32_bf16(af[fm], bfr[fn], acc[fm][fn], 0,0,0);
    if (t < 31){
      if (bn == 0){
        f32x4 w0 = *(const f32x4*)(wqs + k0n + ac);
        f32x4 w1v = *(const f32x4*)(wqs + k0n + ac + 4);
        #pragma unroll
        for (int j=0;j<4;j++)
          xqacc += r0[j]*w0[j] + r1[j]*w1v[j];
      }
      bf16x8 s0;
      #pragma unroll
      for (int j=0;j<4;j++){ s0[j]=f2bf(r0[j]); s0[4+j]=f2bf(r1[j]); }
      *(bf16x8*)(&As[nxt][ar*BK + ac]) = s0;
    }
    __syncthreads();
  }

  // xq: combine the 4 threads per row
  if (bn == 0){
    float s = xqacc;
    s += __shfl_xor(s, 1);
    s += __shfl_xor(s, 2);
    if ((tid & 3) == 0) xq[m0 + ar] = s;
  }

  // epilogue: GELU + dot w2 over this wave's 64 cols -> per-row partial strip
  #pragma unroll
  for (int fm=0;fm<4;fm++){
    #pragma unroll
    for (int j=0;j<4;j++){
      float s = 0.f;
      #pragma unroll
      for (int fn=0;fn<4;fn++){
        float h = acc[fm][fn][j] + b1v[fn];
        float g = 0.5f*h*(1.0f + erff(h*0.70710678118f));
        s += g*w2v[fn];
      }
      s += __shfl_xor(s,1); s += __shfl_xor(s,2);
      s += __shfl_xor(s,4); s += __shfl_xor(s,8);
      if (lo == 0){
        int p = bn*4 + wn;
        gpart[(size_t)p*MQ + m0 + wm*64 + fm*16 + hi*4 + j] = s;
      }
    }
  }
}

// ---- fused w-phase + pooling: 1024 blocks x 64 rows.
__global__ __launch_bounds__(256) void k_wpool(
    const float* __restrict__ x, const float* __restrict__ gpart,
    const float* __restrict__ xqv, const float* __restrict__ wq,
    const float* __restrict__ b2p, const float* __restrict__ lamp,
    const void* __restrict__ maskp, const int* __restrict__ flag,
    const int* __restrict__ lens,
    float* __restrict__ part, float* __restrict__ wsumv)
{
  __shared__ float wrow[64];
  int blk = blockIdx.x, t = threadIdx.x;
  int batch = blk >> 5;            // 32 chunks of 64 rows per batch
  int sBase = (blk & 31) * 64;
  size_t R0 = (size_t)blk * 64;
  if (t < 64){
    size_t r = R0 + t;
    float gsum = b2p[0];
    #pragma unroll
    for (int p=0;p<8;p++) gsum += gpart[(size_t)p*MQ + r];
    float gate = 1.0f/(1.0f+expf(-gsum));
    float qb = wq[DQ];
    float lg = (gate*xqv[r] + qb)*0.03125f;
    float lam = lamp[0];
    float posl = fmaxf(lam,0.f) + log1pf(expf(-fabsf(lam)));
    int L = lens[batch];
    int s = sBase + t;
    float pen = fmaxf((float)L - 1.0f - (float)s, 0.0f);
    int fl = *flag;
    size_t mi_ = (size_t)batch*SQ + s;
    int mm = (fl==2) ? (((const unsigned char*)maskp)[mi_]!=0)
           : (fl==1) ? (((const float*)maskp)[mi_]!=0.0f)
                     : (((const int*)maskp)[mi_]!=0);
    float e = mm ? 0.0f : expf(lg - posl*pen);   // softmax denominator term
    wrow[t] = e*gate;                             // pooling weight
    float ts = e;
    #pragma unroll
    for (int o=1;o<64;o<<=1) ts += __shfl_xor(ts,o);
    if (t==0) wsumv[blk] = ts;
  }
  __syncthreads();

  int d0 = t*4;
  const float* xb = x + R0*DQ + d0;
  f32x4 a = {0.f,0.f,0.f,0.f};
  #pragma unroll 8
  for (int s=0;s<64;s++){
    float w = wrow[s];
    f32x4 v = *(const f32x4*)(xb + (size_t)s*DQ);
    a[0] += w*v[0]; a[1] += w*v[1]; a[2] += w*v[2]; a[3] += w*v[3];
  }
  *(f32x4*)(part + (size_t)blk*DQ + d0) = a;
}

// ---- final: out[b][d] = sum_c part[b*32+c][d] / sum_c wsum[b*32+c]
__global__ __launch_bounds__(256) void k_fin(const float* __restrict__ part,
                                             const float* __restrict__ wsumv,
                                             float* __restrict__ out){
  int i = blockIdx.x*256 + threadIdx.x;   // 32768
  int b = i >> 10, d = i & 1023;
  float den = 0.f;
  #pragma unroll
  for (int c=0;c<32;c++) den += wsumv[b*32+c];
  float s = 0.f;
  #pragma unroll
  for (int c=0;c<32;c++) s += part[((size_t)(b*32+c))*DQ + d];
  out[i] = s/den;
}

extern "C" void kernel_launch(void* const* d_in, const int* in_sizes, int n_in,
                              void* d_out, int out_size, void* d_ws, size_t ws_size,
                              hipStream_t stream)
{
  const float* x    = (const float*)d_in[0];
  const void*  mask = d_in[1];
  const float* w1   = (const float*)d_in[2];
  const float* b1   = (const float*)d_in[3];
  const float* w2   = (const float*)d_in[4];
  const float* b2   = (const float*)d_in[5];
  const float* lam  = (const float*)d_in[6];
  const float* q    = (const float*)d_in[7];
  const float* kw   = (const float*)d_in[8];
  const float* kb   = (const float*)d_in[9];
  char* ws = (char*)d_ws;
  short* w1t   = (short*)ws;                             // 1 MB
  float* wq    = (float*)(ws + (1<<20));                 // 8 KB (1025 floats)
  int*   flag  = (int*)(ws + (1<<20) + 8192);            // 4 B
  int*   lens  = (int*)(ws + (1<<20) + 8448);            // 128 B
  float* wsumv = (float*)(ws + (1<<20) + 12544);         // 4 KB (1024)
  float* xqv   = (float*)(ws + (1<<20) + 32768);         // 256 KB
  float* gpart = (float*)(ws + (2<<20));                 // 2 MB (8 x MQ)
  float* part  = (float*)(ws + (4<<20));                 // 4 MB (1024 x 1024)
  float* out   = (float*)d_out;

  k_det<<<dim3(1), 256, 0, stream>>>((const uint4*)mask, flag);
  k_prep<<<dim3(1185), 256, 0, stream>>>(w1, w1t, kw, kb, q, wq,
                                         mask, flag, lens);
  k_gate<<<dim3((MQ/BM)*(NQ/BN)), 512, 0, stream>>>(x, w1t, wq, w2, b1,
                                                    gpart, xqv);
  k_wpool<<<dim3(MQ/64), 256, 0, stream>>>(x, gpart, xqv, wq, b2, lam,
                                           mask, flag, lens, part, wsumv);
  k_fin<<<dim3((BQ*DQ)/256), 256, 0, stream>>>(part, wsumv, out);
}